// Round 9
// baseline (327.328 us; speedup 1.0000x reference)
//
#include <hip/hip_runtime.h>

// ---------------------------------------------------------------------------
// ContrastiveLoss: loss = mean_i [ 0.5*(LSE_row_i + LSE_col_i) - diag_i ]
// over logits = normalize(img) @ normalize(txt)^T / 0.07, N=8192, D=1024.
// |logit| <= 14.29 -> exp() safe in fp32, no max subtraction needed.
//
// R8: NO-LDS GEMM. For NT layout + mfma_scale 16x16x128, each lane's A/B
// fragment is 32 CONTIGUOUS global bytes (row = lanelo, k = quad*32+[0,32))
// -> load fragments straight to VGPRs (2x dwordx4), skip LDS + barriers
// entirely. K-loop has zero __syncthreads; compiler pipelines 16 loads
// against 16 MFMAs with fine-grained vmcnt (the AITER-style interleave).
// Per-block working set (A,B k-slices 16KB each) is L1/L2-resident; panels
// reused across blocks -> L2 serves repeats.
// R7 lesson: the two-window LDS read pattern had irreducible +4cyc/read
// bank conflicts AND the per-iter vmcnt(0) barrier drain dominated (MfmaUtil
// 26%, VALUBusy 31%, both idle = latency-bound). Removing LDS removes both.
// ---------------------------------------------------------------------------

#define BM 128
#define BN 128
#define BKB 128   // fp8 K-bytes per iteration (one MFMA k-step)

typedef float floatx4 __attribute__((ext_vector_type(4)));
typedef int   intx4   __attribute__((ext_vector_type(4)));
typedef int   intx8   __attribute__((ext_vector_type(8)));

// ---- Kernel 1: row L2-normalize, x16, fp32 -> fp8 e4m3 (contiguous k) ------
// One wave per row (16 floats/lane), 4 rows per block. Rows [0,N)->img,
// [N,2N)->txt. Side duty: zero rowsum/colsum (2N floats) and out.
__global__ __launch_bounds__(256)
void normalize_fp8(const float* __restrict__ img, const float* __restrict__ txt,
                   unsigned int* __restrict__ oimg, unsigned int* __restrict__ otxt,
                   float* __restrict__ sums, float* __restrict__ out, int N) {
    const int gi = blockIdx.x * 256 + threadIdx.x;
    if (gi < 2 * N) sums[gi] = 0.f;
    if (gi == 0) out[0] = 0.f;

    const int gw = blockIdx.x * 4 + (threadIdx.x >> 6);   // row id in [0,2N)
    const int lane = threadIdx.x & 63;
    const float* in = (gw < N) ? img : txt;
    unsigned int* o = (gw < N) ? oimg : otxt;
    const int row = (gw < N) ? gw : gw - N;
    const float4* rp = (const float4*)(in + (size_t)row * 1024);

    float4 v[4];
    float ss = 0.f;
    #pragma unroll
    for (int j = 0; j < 4; ++j) {
        v[j] = rp[j * 64 + lane];
        ss += v[j].x * v[j].x + v[j].y * v[j].y + v[j].z * v[j].z + v[j].w * v[j].w;
    }
    #pragma unroll
    for (int o2 = 1; o2 < 64; o2 <<= 1) ss += __shfl_xor(ss, o2);
    const float inv = 16.0f / fmaxf(sqrtf(ss), 1e-8f);   // x16 quantization scale
    #pragma unroll
    for (int j = 0; j < 4; ++j) {
        int p = __builtin_amdgcn_cvt_pk_fp8_f32(v[j].x * inv, v[j].y * inv, 0, false);
        p = __builtin_amdgcn_cvt_pk_fp8_f32(v[j].z * inv, v[j].w * inv, p, true);
        o[(size_t)row * 256 + j * 64 + lane] = (unsigned int)p;
    }
}

// ---- Kernel 2: 128x128-tile NT MX-fp8 GEMM, direct-to-register fragments ---
__global__ __launch_bounds__(256)
void gemm_exp_kernel(const unsigned char* __restrict__ A,   // img_q [N][K] fp8
                     const unsigned char* __restrict__ B,   // txt_q [N][K] fp8
                     float* __restrict__ rowsum, float* __restrict__ colsum,
                     float* __restrict__ diag, int K, float scale) {
    const int bm = blockIdx.x, bn = blockIdx.y;
    const int tid = threadIdx.x;
    const int lane = tid & 63;
    const int wave = tid >> 6;
    const int quad = lane >> 4;
    const int lanelo = lane & 15;
    const int wrow = (wave >> 1) * 64;   // wave quadrant within 128x128
    const int wcol = (wave & 1) * 64;

    floatx4 acc[4][4] = {};

    // Per-lane fragment base pointers (loop-invariant): row = tile row of
    // fragment tm/tn + lanelo, byte k = quad*32.
    const unsigned char* pa[4];
    const unsigned char* pb[4];
    #pragma unroll
    for (int t = 0; t < 4; ++t) {
        pa[t] = A + (size_t)(bm * BM + wrow + t * 16 + lanelo) * K + quad * 32;
        pb[t] = B + (size_t)(bn * BN + wcol + t * 16 + lanelo) * K + quad * 32;
    }

    for (int k0 = 0; k0 < K; k0 += BKB) {
        intx4 a0[4], a1[4], b0[4], b1[4];
        #pragma unroll
        for (int t = 0; t < 4; ++t) {
            a0[t] = *(const intx4*)(pa[t]);
            a1[t] = *(const intx4*)(pa[t] + 16);
            b0[t] = *(const intx4*)(pb[t]);
            b1[t] = *(const intx4*)(pb[t] + 16);
            pa[t] += BKB; pb[t] += BKB;
        }

        intx8 af[4], bg[4];
        #pragma unroll
        for (int t = 0; t < 4; ++t) {
            af[t] = __builtin_shufflevector(a0[t], a1[t], 0, 1, 2, 3, 4, 5, 6, 7);
            bg[t] = __builtin_shufflevector(b0[t], b1[t], 0, 1, 2, 3, 4, 5, 6, 7);
        }

        #pragma unroll
        for (int tm = 0; tm < 4; ++tm)
            #pragma unroll
            for (int tn = 0; tn < 4; ++tn)
                acc[tm][tn] = __builtin_amdgcn_mfma_scale_f32_16x16x128_f8f6f4(
                    af[tm], bg[tn], acc[tm][tn],
                    0, 0,          // cbsz = fp8 e4m3, blgp = fp8 e4m3
                    0, 127,        // A scale: opsel 0, E8M0 127 = 1.0
                    0, 127);       // B scale: 1.0
    }

    // ---- epilogue: scale, capture diag, exp in place ----
    const int growb = bm * BM + wrow;
    const int gcolb = bn * BN + wcol;

    #pragma unroll
    for (int tm = 0; tm < 4; ++tm)
        #pragma unroll
        for (int tn = 0; tn < 4; ++tn)
            #pragma unroll
            for (int r = 0; r < 4; ++r) {
                const float l = acc[tm][tn][r] * scale;
                const int grow = growb + tm * 16 + quad * 4 + r;
                const int gcol = gcolb + tn * 16 + lanelo;
                if (grow == gcol) diag[grow] = l;
                acc[tm][tn][r] = __expf(l);
            }

    // ---- row sums: reduce over the 16 lanes sharing a row, then atomicAdd ----
    #pragma unroll
    for (int tm = 0; tm < 4; ++tm) {
        floatx4 rs = acc[tm][0] + acc[tm][1] + acc[tm][2] + acc[tm][3];
        #pragma unroll
        for (int r = 0; r < 4; ++r) {
            float v = rs[r];
            v += __shfl_xor(v, 1);
            v += __shfl_xor(v, 2);
            v += __shfl_xor(v, 4);
            v += __shfl_xor(v, 8);
            if (lanelo == 0)
                atomicAdd(&rowsum[growb + tm * 16 + quad * 4 + r], v);
        }
    }

    // ---- col sums: reduce over quads (xor 16, 32), then atomicAdd ----
    #pragma unroll
    for (int tn = 0; tn < 4; ++tn) {
        float cs = 0.f;
        #pragma unroll
        for (int tm = 0; tm < 4; ++tm)
            cs += acc[tm][tn][0] + acc[tm][tn][1] + acc[tm][tn][2] + acc[tm][tn][3];
        cs += __shfl_xor(cs, 16);
        cs += __shfl_xor(cs, 32);
        if (quad == 0)
            atomicAdd(&colsum[gcolb + tn * 16 + lanelo], cs);
    }
}

// ---- Kernel 3: loss = mean( 0.5*(log(rowsum)+log(colsum)) - diag ) ---------
// out zeroed by normalize_fp8 (stream-ordered before this kernel).
__global__ __launch_bounds__(256)
void final_reduce(const float* __restrict__ rowsum, const float* __restrict__ colsum,
                  const float* __restrict__ diag, float* __restrict__ out, int n) {
    const int i = blockIdx.x * 256 + threadIdx.x;
    const int t = threadIdx.x;
    float v = 0.5f * (logf(rowsum[i]) + logf(colsum[i])) - diag[i];
    #pragma unroll
    for (int o = 1; o < 64; o <<= 1) v += __shfl_xor(v, o);
    __shared__ float ws[4];
    if ((t & 63) == 0) ws[t >> 6] = v;
    __syncthreads();
    if (t == 0) atomicAdd(out, (ws[0] + ws[1] + ws[2] + ws[3]) / (float)n);
}

extern "C" void kernel_launch(void* const* d_in, const int* in_sizes, int n_in,
                              void* d_out, int out_size, void* d_ws, size_t ws_size,
                              hipStream_t stream) {
    const float* img = (const float*)d_in[0];
    const float* txt = (const float*)d_in[1];
    float* out = (float*)d_out;

    const int D = 1024;
    const int N = in_sizes[0] / D;   // 8192

    unsigned char* imgq = (unsigned char*)d_ws;
    unsigned char* txtq = imgq + (size_t)N * D;
    float* rowsum = (float*)(txtq + (size_t)N * D);   // rowsum[N] ++ colsum[N]
    float* colsum = rowsum + N;
    float* diag = colsum + N;

    normalize_fp8<<<2 * N / 4, 256, 0, stream>>>(img, txt, (unsigned int*)imgq,
                                                 (unsigned int*)txtq, rowsum, out, N);

    dim3 grid(N / BM, N / BN);
    // acc = sum of (16a)(16b) = 256*cos; scale undoes 256 and applies 1/T.
    gemm_exp_kernel<<<grid, 256, 0, stream>>>(imgq, txtq, rowsum, colsum, diag,
                                              D, 1.0f / (256.0f * 0.07f));
    final_reduce<<<N / 256, 256, 0, stream>>>(rowsum, colsum, diag, out, N);
}

// Round 10
// 208.745 us; speedup vs baseline: 1.5681x; 1.5681x over previous
//
#include <hip/hip_runtime.h>

// ---------------------------------------------------------------------------
// ContrastiveLoss: loss = mean_i [ 0.5*(LSE_row_i + LSE_col_i) - diag_i ]
// over logits = normalize(img) @ normalize(txt)^T / 0.07, N=8192, D=1024.
// |logit| <= 14.29 -> exp() safe in fp32, no max subtraction needed.
//
// R9: switch MFMA to mfma_scale_f32_32x32x64_f8f6f4 (scales=1.0), wave tile
// 64x64 = 2x2 of 32x32, k-steps sequential. Same MFMA rate; per-wave regs
// drop ~140 -> ~115 (acc 64 AGPR + 32 live frag VGPRs) -> 4 waves/SIMD
// instead of 3 (occupancy was the R7 limiter: MfmaUtil 26%, VALU 31%, both
// idle = barrier-latency-bound at 3 waves/SIMD).
// R8 lesson: no-LDS direct-global fragments thrash L1 (244us, Mfma 11%) -
// LDS staging is mandatory for cross-wave capture.
// LDS geometry/staging byte-identical to R5/R7 (proven): BK=128 as two 64B
// windows, 4x16B slots, slot = chunk ^ ((row>>1)&3); 32x32 lane fragment =
// 32 contiguous k-bytes (row = lane&31, k-half = lane>>5) = chunks
// 2*(lane>>5), +1 -> b128 at addr, addr^16.
// R1 lesson: staging lane->addr segment-monotone per quarter-wave.
// 32x32 C/D layout (m74/m101): col = lane&31, row = (r&3)+8*(r>>2)+4*(lane>>5).
// ---------------------------------------------------------------------------

#define BM 128
#define BN 128
#define BKB 128   // fp8 K-bytes per iteration (two 32x32x64 k-steps)

typedef float floatx16 __attribute__((ext_vector_type(16)));
typedef int   intx4    __attribute__((ext_vector_type(4)));
typedef int   intx8    __attribute__((ext_vector_type(8)));

__device__ __forceinline__ void gload_lds16(const unsigned char* g, unsigned char* lds) {
    __builtin_amdgcn_global_load_lds(
        (const __attribute__((address_space(1))) void*)g,
        (__attribute__((address_space(3))) void*)lds,
        16, 0, 0);
}

// ---- Kernel 1: row L2-normalize, x16, fp32 -> fp8 e4m3 (contiguous k) ------
// One wave per row (16 floats/lane), 4 rows per block. Rows [0,N)->img,
// [N,2N)->txt. Side duty: zero rowsum/colsum (2N floats) and out.
__global__ __launch_bounds__(256)
void normalize_fp8(const float* __restrict__ img, const float* __restrict__ txt,
                   unsigned int* __restrict__ oimg, unsigned int* __restrict__ otxt,
                   float* __restrict__ sums, float* __restrict__ out, int N) {
    const int gi = blockIdx.x * 256 + threadIdx.x;
    if (gi < 2 * N) sums[gi] = 0.f;
    if (gi == 0) out[0] = 0.f;

    const int gw = blockIdx.x * 4 + (threadIdx.x >> 6);   // row id in [0,2N)
    const int lane = threadIdx.x & 63;
    const float* in = (gw < N) ? img : txt;
    unsigned int* o = (gw < N) ? oimg : otxt;
    const int row = (gw < N) ? gw : gw - N;
    const float4* rp = (const float4*)(in + (size_t)row * 1024);

    float4 v[4];
    float ss = 0.f;
    #pragma unroll
    for (int j = 0; j < 4; ++j) {
        v[j] = rp[j * 64 + lane];
        ss += v[j].x * v[j].x + v[j].y * v[j].y + v[j].z * v[j].z + v[j].w * v[j].w;
    }
    #pragma unroll
    for (int o2 = 1; o2 < 64; o2 <<= 1) ss += __shfl_xor(ss, o2);
    const float inv = 16.0f / fmaxf(sqrtf(ss), 1e-8f);   // x16 quantization scale
    #pragma unroll
    for (int j = 0; j < 4; ++j) {
        int p = __builtin_amdgcn_cvt_pk_fp8_f32(v[j].x * inv, v[j].y * inv, 0, false);
        p = __builtin_amdgcn_cvt_pk_fp8_f32(v[j].z * inv, v[j].w * inv, p, true);
        o[(size_t)row * 256 + j * 64 + lane] = (unsigned int)p;
    }
}

// ---- Kernel 2: 128x128-tile NT MX-fp8 GEMM (32x32x64) + fused epilogue -----
__global__ __launch_bounds__(256, 4)
void gemm_exp_kernel(const unsigned char* __restrict__ A,   // img_q [N][K] fp8
                     const unsigned char* __restrict__ B,   // txt_q [N][K] fp8
                     float* __restrict__ rowsum, float* __restrict__ colsum,
                     float* __restrict__ diag, int K, float scale) {
    // LDS: per matrix, 2 windows x [128 rows][64B], slot = chunk ^ ((R>>1)&3).
    __shared__ unsigned char As[2 * BM * 64];   // 16 KB
    __shared__ unsigned char Bs[2 * BN * 64];   // 16 KB

    const int bm = blockIdx.x, bn = blockIdx.y;
    const int tid = threadIdx.x;
    const int lane = tid & 63;
    const int wave = tid >> 6;
    const int half = lane >> 5;         // 0/1: k-half owner for 32x32 frags
    const int l31 = lane & 31;
    const int wrow = (wave >> 1) * 64;  // wave quadrant within 128x128
    const int wcol = (wave & 1) * 64;

    floatx16 acc[2][2] = {};

    // Staging (per window): chunk c = wave*128 + lane (and +64); LDS slot =
    // c&3 of row c>>2; global chunk fetched = slot ^ swz(row).
    const int c0 = wave * 128 + lane;
    const int c1 = c0 + 64;
    const int r0 = c0 >> 2, r1 = c1 >> 2;
    const int kg0 = ((c0 & 3) ^ ((r0 >> 1) & 3)) * 16;   // byte in 64B window
    const int kg1 = ((c1 & 3) ^ ((r1 >> 1) & 3)) * 16;

    const unsigned char* pa0 = A + (size_t)bm * BM * K + (size_t)r0 * K + kg0;
    const unsigned char* pa1 = A + (size_t)bm * BM * K + (size_t)r1 * K + kg1;
    const unsigned char* pb0 = B + (size_t)bn * BN * K + (size_t)r0 * K + kg0;
    const unsigned char* pb1 = B + (size_t)bn * BN * K + (size_t)r1 * K + kg1;
    unsigned char* dA0 = As + c0 * 16;
    unsigned char* dA1 = As + c1 * 16;
    unsigned char* dB0 = Bs + c0 * 16;
    unsigned char* dB1 = Bs + c1 * 16;

    // Fragment LDS offsets (window-0 base): row R = wtile + t*32 + l31,
    // first chunk cf = 2*half, slot = cf ^ swz(R); second chunk at addr^16.
    int aoff[2], boff[2];
    #pragma unroll
    for (int t = 0; t < 2; ++t) {
        const int Ra = wrow + t * 32 + l31;
        const int Rb = wcol + t * 32 + l31;
        const int cf = half * 2;
        aoff[t] = Ra * 64 + ((cf ^ ((Ra >> 1) & 3)) * 16);
        boff[t] = Rb * 64 + ((cf ^ ((Rb >> 1) & 3)) * 16);
    }

    for (int k0 = 0; k0 < K; k0 += BKB) {
        #pragma unroll
        for (int w = 0; w < 2; ++w) {
            gload_lds16(pa0 + w * 64, dA0 + w * 8192);
            gload_lds16(pa1 + w * 64, dA1 + w * 8192);
            gload_lds16(pb0 + w * 64, dB0 + w * 8192);
            gload_lds16(pb1 + w * 64, dB1 + w * 8192);
        }
        pa0 += BKB; pa1 += BKB; pb0 += BKB; pb1 += BKB;
        __syncthreads();

        #pragma unroll
        for (int s = 0; s < 2; ++s) {        // k-step (64 k-bytes each)
            const int wofs = s * 8192;
            intx8 af[2], bg[2];
            #pragma unroll
            for (int t = 0; t < 2; ++t) {
                const intx4 alo = *(const intx4*)(As + wofs + aoff[t]);
                const intx4 ahi = *(const intx4*)(As + wofs + (aoff[t] ^ 16));
                af[t] = __builtin_shufflevector(alo, ahi, 0, 1, 2, 3, 4, 5, 6, 7);
                const intx4 blo = *(const intx4*)(Bs + wofs + boff[t]);
                const intx4 bhi = *(const intx4*)(Bs + wofs + (boff[t] ^ 16));
                bg[t] = __builtin_shufflevector(blo, bhi, 0, 1, 2, 3, 4, 5, 6, 7);
            }
            #pragma unroll
            for (int tm = 0; tm < 2; ++tm)
                #pragma unroll
                for (int tn = 0; tn < 2; ++tn)
                    acc[tm][tn] = __builtin_amdgcn_mfma_scale_f32_32x32x64_f8f6f4(
                        af[tm], bg[tn], acc[tm][tn],
                        0, 0,          // cbsz = fp8 e4m3, blgp = fp8 e4m3
                        0, 127,        // A scale: 1.0
                        0, 127);       // B scale: 1.0
        }
        __syncthreads();
    }

    // ---- epilogue: scale, capture diag, exp in place ----
    // 32x32 C/D: col = l31, row = (r&3) + 8*(r>>2) + 4*half  (m74/m101).
    const int growb = bm * BM + wrow;
    const int gcolb = bn * BN + wcol;

    #pragma unroll
    for (int tm = 0; tm < 2; ++tm)
        #pragma unroll
        for (int tn = 0; tn < 2; ++tn)
            #pragma unroll
            for (int r = 0; r < 16; ++r) {
                const float l = acc[tm][tn][r] * scale;
                const int grow = growb + tm * 32 + (r & 3) + 8 * (r >> 2) + 4 * half;
                const int gcol = gcolb + tn * 32 + l31;
                if (grow == gcol) diag[grow] = l;
                acc[tm][tn][r] = __expf(l);
            }

    // ---- row sums: reduce over the 32 lanes (cols) of each half-wave -------
    #pragma unroll
    for (int tm = 0; tm < 2; ++tm) {
        #pragma unroll
        for (int r = 0; r < 16; ++r) {
            float v = acc[tm][0][r] + acc[tm][1][r];
            v += __shfl_xor(v, 1);
            v += __shfl_xor(v, 2);
            v += __shfl_xor(v, 4);
            v += __shfl_xor(v, 8);
            v += __shfl_xor(v, 16);
            if (l31 == 0)
                atomicAdd(&rowsum[growb + tm * 32 + (r & 3) + 8 * (r >> 2) + 4 * half], v);
        }
    }

    // ---- col sums: per-lane partial over its 16 rows, add other half, add --
    #pragma unroll
    for (int tn = 0; tn < 2; ++tn) {
        float cs = 0.f;
        #pragma unroll
        for (int tm = 0; tm < 2; ++tm)
            #pragma unroll
            for (int r = 0; r < 16; ++r)
                cs += acc[tm][tn][r];
        cs += __shfl_xor(cs, 32);
        if (half == 0)
            atomicAdd(&colsum[gcolb + tn * 32 + l31], cs);
    }
}

// ---- Kernel 3: loss = mean( 0.5*(log(rowsum)+log(colsum)) - diag ) ---------
// out zeroed by normalize_fp8 (stream-ordered before this kernel).
__global__ __launch_bounds__(256)
void final_reduce(const float* __restrict__ rowsum, const float* __restrict__ colsum,
                  const float* __restrict__ diag, float* __restrict__ out, int n) {
    const int i = blockIdx.x * 256 + threadIdx.x;
    const int t = threadIdx.x;
    float v = 0.5f * (logf(rowsum[i]) + logf(colsum[i])) - diag[i];
    #pragma unroll
    for (int o = 1; o < 64; o <<= 1) v += __shfl_xor(v, o);
    __shared__ float ws[4];
    if ((t & 63) == 0) ws[t >> 6] = v;
    __syncthreads();
    if (t == 0) atomicAdd(out, (ws[0] + ws[1] + ws[2] + ws[3]) / (float)n);
}

extern "C" void kernel_launch(void* const* d_in, const int* in_sizes, int n_in,
                              void* d_out, int out_size, void* d_ws, size_t ws_size,
                              hipStream_t stream) {
    const float* img = (const float*)d_in[0];
    const float* txt = (const float*)d_in[1];
    float* out = (float*)d_out;

    const int D = 1024;
    const int N = in_sizes[0] / D;   // 8192

    unsigned char* imgq = (unsigned char*)d_ws;
    unsigned char* txtq = imgq + (size_t)N * D;
    float* rowsum = (float*)(txtq + (size_t)N * D);   // rowsum[N] ++ colsum[N]
    float* colsum = rowsum + N;
    float* diag = colsum + N;

    normalize_fp8<<<2 * N / 4, 256, 0, stream>>>(img, txt, (unsigned int*)imgq,
                                                 (unsigned int*)txtq, rowsum, out, N);

    dim3 grid(N / BM, N / BN);
    // acc = sum of (16a)(16b) = 256*cos; scale undoes 256 and applies 1/T.
    gemm_exp_kernel<<<grid, 256, 0, stream>>>(imgq, txtq, rowsum, colsum, diag,
                                              D, 1.0f / (256.0f * 0.07f));
    final_reduce<<<N / 256, 256, 0, stream>>>(rowsum, colsum, diag, out, N);
}

// Round 11
// 189.260 us; speedup vs baseline: 1.7295x; 1.1030x over previous
//
#include <hip/hip_runtime.h>

// ---------------------------------------------------------------------------
// ContrastiveLoss: loss = mean_i [ 0.5*(LSE_row_i + LSE_col_i) - diag_i ]
// over logits = normalize(img) @ normalize(txt)^T / 0.07, N=8192, D=1024.
// |logit| <= 14.29 -> exp() safe in fp32, no max subtraction needed.
//
// R10: R7 structure (16x16x128 MX-fp8, best GEMM 108.5us) + producer-side
// EVEN/ODD CHUNK INTERLEAVE to kill the 8.39e6 bank conflicts. Normalize
// stores each 128B k-window as [c0,c2,c4,c6 | c1,c3,c5,c7] (16B chunks).
// Lane-quad q's MFMA fragment (orig chunks 2q,2q+1) becomes position q of
// half A + position q of half B -> both b128 fragment reads use the R5
// measured-zero-conflict geometry (slot = q ^ swz(R), one 64B window per
// read; second read = first + 8192, bank-identical pattern).
// R6-R9 lesson: two-window reads where quad pairs {0,2},{1,3} hit identical
// in-window offsets 8192 apart collide pairwise (+2 cyc per b128, 13.7us).
// R9 lesson: occupancy was not the limiter (39% occ but 121us); R8 lesson:
// no-LDS thrashes L1 (244us). R1 lesson: staging lane->addr must stay
// segment-monotone per quarter-wave. Staging code = R7 verbatim.
// ---------------------------------------------------------------------------

#define BM 128
#define BN 128
#define BKB 128   // fp8 K-bytes per iteration (one MFMA k-step)

typedef float floatx4 __attribute__((ext_vector_type(4)));
typedef int   intx4   __attribute__((ext_vector_type(4)));
typedef int   intx8   __attribute__((ext_vector_type(8)));

__device__ __forceinline__ void gload_lds16(const unsigned char* g, unsigned char* lds) {
    __builtin_amdgcn_global_load_lds(
        (const __attribute__((address_space(1))) void*)g,
        (__attribute__((address_space(3))) void*)lds,
        16, 0, 0);
}

// ---- Kernel 1: row L2-normalize, x16, fp32 -> fp8 e4m3, chunk-interleaved --
// One wave per row (16 floats/lane), 4 rows per block. Rows [0,N)->img,
// [N,2N)->txt. Output dword d (4 fp8) of a 256-dword row is stored at
// d' = (d & ~31) | (p*4 + (d&3)) where chunk c = (d>>2)&7 and
// p = (c&1)*4 + (c>>1)   (even chunks -> first 64B half, odd -> second).
// Side duty: zero rowsum/colsum (2N floats) and out.
__global__ __launch_bounds__(256)
void normalize_fp8(const float* __restrict__ img, const float* __restrict__ txt,
                   unsigned int* __restrict__ oimg, unsigned int* __restrict__ otxt,
                   float* __restrict__ sums, float* __restrict__ out, int N) {
    const int gi = blockIdx.x * 256 + threadIdx.x;
    if (gi < 2 * N) sums[gi] = 0.f;
    if (gi == 0) out[0] = 0.f;

    const int gw = blockIdx.x * 4 + (threadIdx.x >> 6);   // row id in [0,2N)
    const int lane = threadIdx.x & 63;
    const float* in = (gw < N) ? img : txt;
    unsigned int* o = (gw < N) ? oimg : otxt;
    const int row = (gw < N) ? gw : gw - N;
    const float4* rp = (const float4*)(in + (size_t)row * 1024);

    float4 v[4];
    float ss = 0.f;
    #pragma unroll
    for (int j = 0; j < 4; ++j) {
        v[j] = rp[j * 64 + lane];
        ss += v[j].x * v[j].x + v[j].y * v[j].y + v[j].z * v[j].z + v[j].w * v[j].w;
    }
    #pragma unroll
    for (int o2 = 1; o2 < 64; o2 <<= 1) ss += __shfl_xor(ss, o2);
    const float inv = 16.0f / fmaxf(sqrtf(ss), 1e-8f);   // x16 quantization scale
    #pragma unroll
    for (int j = 0; j < 4; ++j) {
        int p = __builtin_amdgcn_cvt_pk_fp8_f32(v[j].x * inv, v[j].y * inv, 0, false);
        p = __builtin_amdgcn_cvt_pk_fp8_f32(v[j].z * inv, v[j].w * inv, p, true);
        const int d = j * 64 + lane;
        const int c = (d >> 2) & 7;
        const int pp = (c & 1) * 4 + (c >> 1);
        const int dp = (d & ~31) | (pp * 4 + (d & 3));
        o[(size_t)row * 256 + dp] = (unsigned int)p;
    }
}

// ---- Kernel 2: 128x128-tile NT MX-fp8 GEMM + fused exp/row-col sums/diag ---
__global__ __launch_bounds__(256)
void gemm_exp_kernel(const unsigned char* __restrict__ A,   // img_q [N][K] fp8 (interleaved)
                     const unsigned char* __restrict__ B,   // txt_q [N][K] fp8 (interleaved)
                     float* __restrict__ rowsum, float* __restrict__ colsum,
                     float* __restrict__ diag, int K, float scale) {
    // LDS: per matrix, 2 windows x [128 rows][64B], slot = chunk ^ ((R>>1)&3).
    __shared__ unsigned char As[2 * BM * 64];   // 16 KB
    __shared__ unsigned char Bs[2 * BN * 64];   // 16 KB

    const int bm = blockIdx.x, bn = blockIdx.y;
    const int tid = threadIdx.x;
    const int lane = tid & 63;
    const int wave = tid >> 6;
    const int quad = lane >> 4;
    const int lanelo = lane & 15;
    const int wrow = (wave >> 1) * 64;   // wave quadrant within 128x128
    const int wcol = (wave & 1) * 64;

    floatx4 acc[4][4] = {};

    // Staging (R7 verbatim): chunk c = wave*128 + lane (and +64); LDS slot =
    // c&3 of row c>>2; global chunk fetched = slot ^ swz(row).
    const int c0 = wave * 128 + lane;
    const int c1 = c0 + 64;
    const int r0 = c0 >> 2, r1 = c1 >> 2;
    const int kg0 = ((c0 & 3) ^ ((r0 >> 1) & 3)) * 16;   // byte in 64B window
    const int kg1 = ((c1 & 3) ^ ((r1 >> 1) & 3)) * 16;

    const unsigned char* pa0 = A + (size_t)bm * BM * K + (size_t)r0 * K + kg0;
    const unsigned char* pa1 = A + (size_t)bm * BM * K + (size_t)r1 * K + kg1;
    const unsigned char* pb0 = B + (size_t)bn * BN * K + (size_t)r0 * K + kg0;
    const unsigned char* pb1 = B + (size_t)bn * BN * K + (size_t)r1 * K + kg1;
    unsigned char* dA0 = As + c0 * 16;
    unsigned char* dA1 = As + c1 * 16;
    unsigned char* dB0 = Bs + c0 * 16;
    unsigned char* dB1 = Bs + c1 * 16;

    // Fragment LDS offsets (R5 geometry): slot = quad ^ swz(R) of a single
    // 64B window. Read1 = window0 (even chunks = k[32q..32q+16)),
    // read2 = +8192 (odd chunks = k[32q+16..32q+32)).
    int aoff[4], boff[4];
    #pragma unroll
    for (int t = 0; t < 4; ++t) {
        const int Ra = wrow + t * 16 + lanelo;
        const int Rb = wcol + t * 16 + lanelo;
        aoff[t] = Ra * 64 + ((quad ^ ((Ra >> 1) & 3)) * 16);
        boff[t] = Rb * 64 + ((quad ^ ((Rb >> 1) & 3)) * 16);
    }

    for (int k0 = 0; k0 < K; k0 += BKB) {
        #pragma unroll
        for (int w = 0; w < 2; ++w) {
            gload_lds16(pa0 + w * 64, dA0 + w * 8192);
            gload_lds16(pa1 + w * 64, dA1 + w * 8192);
            gload_lds16(pb0 + w * 64, dB0 + w * 8192);
            gload_lds16(pb1 + w * 64, dB1 + w * 8192);
        }
        pa0 += BKB; pa1 += BKB; pb0 += BKB; pb1 += BKB;
        __syncthreads();

        intx8 af[4], bg[4];
        #pragma unroll
        for (int t = 0; t < 4; ++t) {
            const intx4 alo = *(const intx4*)(As + aoff[t]);
            const intx4 ahi = *(const intx4*)(As + 8192 + aoff[t]);
            af[t] = __builtin_shufflevector(alo, ahi, 0, 1, 2, 3, 4, 5, 6, 7);
            const intx4 blo = *(const intx4*)(Bs + boff[t]);
            const intx4 bhi = *(const intx4*)(Bs + 8192 + boff[t]);
            bg[t] = __builtin_shufflevector(blo, bhi, 0, 1, 2, 3, 4, 5, 6, 7);
        }

        #pragma unroll
        for (int tm = 0; tm < 4; ++tm)
            #pragma unroll
            for (int tn = 0; tn < 4; ++tn)
                acc[tm][tn] = __builtin_amdgcn_mfma_scale_f32_16x16x128_f8f6f4(
                    af[tm], bg[tn], acc[tm][tn],
                    0, 0,          // cbsz = fp8 e4m3, blgp = fp8 e4m3
                    0, 127,        // A scale: 1.0
                    0, 127);       // B scale: 1.0
        __syncthreads();
    }

    // ---- epilogue: scale, capture diag, exp in place ----
    const int growb = bm * BM + wrow;
    const int gcolb = bn * BN + wcol;

    #pragma unroll
    for (int tm = 0; tm < 4; ++tm)
        #pragma unroll
        for (int tn = 0; tn < 4; ++tn)
            #pragma unroll
            for (int r = 0; r < 4; ++r) {
                const float l = acc[tm][tn][r] * scale;
                const int grow = growb + tm * 16 + quad * 4 + r;
                const int gcol = gcolb + tn * 16 + lanelo;
                if (grow == gcol) diag[grow] = l;
                acc[tm][tn][r] = __expf(l);
            }

    // ---- row sums: reduce over the 16 lanes sharing a row, then atomicAdd ----
    #pragma unroll
    for (int tm = 0; tm < 4; ++tm) {
        floatx4 rs = acc[tm][0] + acc[tm][1] + acc[tm][2] + acc[tm][3];
        #pragma unroll
        for (int r = 0; r < 4; ++r) {
            float v = rs[r];
            v += __shfl_xor(v, 1);
            v += __shfl_xor(v, 2);
            v += __shfl_xor(v, 4);
            v += __shfl_xor(v, 8);
            if (lanelo == 0)
                atomicAdd(&rowsum[growb + tm * 16 + quad * 4 + r], v);
        }
    }

    // ---- col sums: reduce over quads (xor 16, 32), then atomicAdd ----
    #pragma unroll
    for (int tn = 0; tn < 4; ++tn) {
        float cs = 0.f;
        #pragma unroll
        for (int tm = 0; tm < 4; ++tm)
            cs += acc[tm][tn][0] + acc[tm][tn][1] + acc[tm][tn][2] + acc[tm][tn][3];
        cs += __shfl_xor(cs, 16);
        cs += __shfl_xor(cs, 32);
        if (quad == 0)
            atomicAdd(&colsum[gcolb + tn * 16 + lanelo], cs);
    }
}

// ---- Kernel 3: loss = mean( 0.5*(log(rowsum)+log(colsum)) - diag ) ---------
// out zeroed by normalize_fp8 (stream-ordered before this kernel).
__global__ __launch_bounds__(256)
void final_reduce(const float* __restrict__ rowsum, const float* __restrict__ colsum,
                  const float* __restrict__ diag, float* __restrict__ out, int n) {
    const int i = blockIdx.x * 256 + threadIdx.x;
    const int t = threadIdx.x;
    float v = 0.5f * (logf(rowsum[i]) + logf(colsum[i])) - diag[i];
    #pragma unroll
    for (int o = 1; o < 64; o <<= 1) v += __shfl_xor(v, o);
    __shared__ float ws[4];
    if ((t & 63) == 0) ws[t >> 6] = v;
    __syncthreads();
    if (t == 0) atomicAdd(out, (ws[0] + ws[1] + ws[2] + ws[3]) / (float)n);
}

extern "C" void kernel_launch(void* const* d_in, const int* in_sizes, int n_in,
                              void* d_out, int out_size, void* d_ws, size_t ws_size,
                              hipStream_t stream) {
    const float* img = (const float*)d_in[0];
    const float* txt = (const float*)d_in[1];
    float* out = (float*)d_out;

    const int D = 1024;
    const int N = in_sizes[0] / D;   // 8192

    unsigned char* imgq = (unsigned char*)d_ws;
    unsigned char* txtq = imgq + (size_t)N * D;
    float* rowsum = (float*)(txtq + (size_t)N * D);   // rowsum[N] ++ colsum[N]
    float* colsum = rowsum + N;
    float* diag = colsum + N;

    normalize_fp8<<<2 * N / 4, 256, 0, stream>>>(img, txt, (unsigned int*)imgq,
                                                 (unsigned int*)txtq, rowsum, out, N);

    dim3 grid(N / BM, N / BN);
    // acc = sum of (16a)(16b) = 256*cos; scale undoes 256 and applies 1/T.
    gemm_exp_kernel<<<grid, 256, 0, stream>>>(imgq, txtq, rowsum, colsum, diag,
                                              D, 1.0f / (256.0f * 0.07f));
    final_reduce<<<N / 256, 256, 0, stream>>>(rowsum, colsum, diag, out, N);
}